// Round 1
// baseline (350.514 us; speedup 1.0000x reference)
//
#include <hip/hip_runtime.h>
#include <cmath>

// Problem constants
// L=1024, N=2, E=1024, H=16, d=64, B*H=32 heads, chunk C=64, NC=16 chunks
// q/k/v head layout: [b=32][l=1024][d=64] f32
// attn buffer: [m=2048][n=1024] f32 row-major (m = l*2 + n_batch)

#define EPS 1e-6f

// ---------------------------------------------------------------------------
// GEMM: C[m][n] = sum_k A[m][k] * B[n][k] + bias[n]   (M=2048, N=1024, K=1024)
// MODE 0: plain row-major write to out (final projection, out = d_out)
// MODE 1: phi(x)=elu(x)+1 applied, write to head layout (q, k)
// MODE 2: no phi, write to head layout (v)
// 64x64 tile, 256 threads, 4x4 per thread, K-step 16, simple double-load.
// ---------------------------------------------------------------------------
template<int MODE>
__global__ __launch_bounds__(256) void gemm_bt(const float* __restrict__ A,
                                               const float* __restrict__ B,
                                               const float* __restrict__ bias,
                                               float* __restrict__ out) {
    __shared__ float As[16][64];
    __shared__ float Bs[16][64];
    int tid = threadIdx.x;
    int tx = tid & 15, ty = tid >> 4;
    int brow = blockIdx.y * 64, bcol = blockIdx.x * 64;
    int lrow = tid >> 2;        // 0..63
    int lk   = (tid & 3) << 2;  // 0,4,8,12
    const float* Ap = A + (size_t)(brow + lrow) * 1024 + lk;
    const float* Bp = B + (size_t)(bcol + lrow) * 1024 + lk;

    float acc[4][4] = {};
    float4 av = *(const float4*)(Ap);
    float4 bv = *(const float4*)(Bp);
    for (int k0 = 0; k0 < 1024; k0 += 16) {
        As[lk+0][lrow] = av.x; As[lk+1][lrow] = av.y;
        As[lk+2][lrow] = av.z; As[lk+3][lrow] = av.w;
        Bs[lk+0][lrow] = bv.x; Bs[lk+1][lrow] = bv.y;
        Bs[lk+2][lrow] = bv.z; Bs[lk+3][lrow] = bv.w;
        __syncthreads();
        if (k0 + 16 < 1024) {
            av = *(const float4*)(Ap + k0 + 16);
            bv = *(const float4*)(Bp + k0 + 16);
        }
        #pragma unroll
        for (int kk = 0; kk < 16; kk++) {
            float a[4], bb[4];
            #pragma unroll
            for (int i = 0; i < 4; i++) a[i] = As[kk][ty*4 + i];
            #pragma unroll
            for (int j = 0; j < 4; j++) bb[j] = Bs[kk][tx*4 + j];
            #pragma unroll
            for (int i = 0; i < 4; i++)
                #pragma unroll
                for (int j = 0; j < 4; j++)
                    acc[i][j] += a[i] * bb[j];
        }
        __syncthreads();
    }

    #pragma unroll
    for (int i = 0; i < 4; i++) {
        int m = brow + ty*4 + i;
        #pragma unroll
        for (int j = 0; j < 4; j++) {
            int n = bcol + tx*4 + j;
            float v = acc[i][j] + bias[n];
            if (MODE == 1) v = (v > 0.f) ? v + 1.f : expf(v);
            if (MODE == 0) {
                out[(size_t)m * 1024 + n] = v;
            } else {
                int l  = m >> 1, nb = m & 1;
                int h  = n >> 6, dd = n & 63;
                out[(size_t)((nb*16 + h) * 1024 + l) * 64 + dd] = v;
            }
        }
    }
}

// ---------------------------------------------------------------------------
// Per-(head, chunk) KV outer-product sums: Sc[b][c][d][e] = sum_s k[s][d]*v[s][e]
// zc[b][c][d] = sum_s k[s][d]
// ---------------------------------------------------------------------------
__global__ __launch_bounds__(256) void chunk_sums(const float* __restrict__ kh,
                                                  const float* __restrict__ vh,
                                                  float* __restrict__ Sc,
                                                  float* __restrict__ zc) {
    int c = blockIdx.x, b = blockIdx.y, tid = threadIdx.x;
    __shared__ float Kl[64][64];
    __shared__ float Vl[64][64];
    const float* Kg = kh + (size_t)(b*1024 + c*64) * 64;
    const float* Vg = vh + (size_t)(b*1024 + c*64) * 64;
    for (int i = tid; i < 1024; i += 256) {
        ((float4*)Kl)[i] = ((const float4*)Kg)[i];
        ((float4*)Vl)[i] = ((const float4*)Vg)[i];
    }
    __syncthreads();
    int e = tid & 63, d0 = (tid >> 6) * 16;
    float s[16] = {};
    for (int ss = 0; ss < 64; ss++) {
        float ve = Vl[ss][e];
        #pragma unroll
        for (int i = 0; i < 16; i++) s[i] += Kl[ss][d0 + i] * ve;
    }
    float* So = Sc + (size_t)(b*16 + c) * 4096;
    #pragma unroll
    for (int i = 0; i < 16; i++) So[(d0 + i) * 64 + e] = s[i];
    if (tid < 64) {
        float z = 0.f;
        for (int ss = 0; ss < 64; ss++) z += Kl[ss][tid];
        zc[(size_t)(b*16 + c) * 64 + tid] = z;
    }
}

// ---------------------------------------------------------------------------
// In-place exclusive prefix over chunks (per head): Sc, zc -> exclusive prefix
// ---------------------------------------------------------------------------
__global__ __launch_bounds__(256) void prefix_chunks(float* __restrict__ Sc,
                                                     float* __restrict__ zc) {
    int b = blockIdx.x, tid = threadIdx.x;
    size_t base = (size_t)b * 16 * 4096 + (size_t)tid * 16;
    float run[16] = {};
    for (int c = 0; c < 16; c++) {
        float* p = Sc + base + (size_t)c * 4096;
        #pragma unroll
        for (int i = 0; i < 16; i++) {
            float t = p[i];
            p[i] = run[i];
            run[i] += t;
        }
    }
    if (tid < 64) {
        float rz = 0.f;
        for (int c = 0; c < 16; c++) {
            size_t idx = ((size_t)b*16 + c) * 64 + tid;
            float t = zc[idx];
            zc[idx] = rz;
            rz += t;
        }
    }
}

// ---------------------------------------------------------------------------
// Per-(head, chunk) attention:
//   P[t][s]  = phiQ[t] . phiK[s]
//   num[t]   = phiQ[t] @ S_prev + sum_{s<=t} P[t][s] * V[s]
//   den[t]   = phiQ[t] . z_prev + sum_{s<=t} P[t][s]
//   attn[l*2+nb][h*64+e] = num[t][e] / (den[t] + eps)
// ---------------------------------------------------------------------------
__global__ __launch_bounds__(256) void attn_chunk(const float* __restrict__ qh,
                                                  const float* __restrict__ kh,
                                                  const float* __restrict__ vh,
                                                  const float* __restrict__ Sp,
                                                  const float* __restrict__ zp,
                                                  float* __restrict__ attn) {
    int c = blockIdx.x, b = blockIdx.y, tid = threadIdx.x;
    int lane = tid & 63, wv = tid >> 6;
    __shared__ float Qt[64][64];   // Qt[d][t] (transposed)
    __shared__ float KV[64][64];   // K rows, then reloaded with V rows
    __shared__ float P[64][65];    // P[t][s], padded
    __shared__ float den[64];

    const float* Qg = qh + (size_t)(b*1024 + c*64) * 64;
    const float* Kg = kh + (size_t)(b*1024 + c*64) * 64;
    const float* Vg = vh + (size_t)(b*1024 + c*64) * 64;

    // stage Q (transposed) and K
    for (int i = tid; i < 1024; i += 256) {
        int t = i >> 4;            // row 0..63
        int d4 = (i & 15) << 2;    // 0..60
        float4 qv = *(const float4*)&Qg[t*64 + d4];
        Qt[d4+0][t] = qv.x; Qt[d4+1][t] = qv.y;
        Qt[d4+2][t] = qv.z; Qt[d4+3][t] = qv.w;
        *(float4*)&KV[t][d4] = *(const float4*)&Kg[t*64 + d4];
    }
    __syncthreads();

    // P[t][s] for this wave's 16 s values
    {
        int t = lane, s0 = wv * 16;
        float acc[16];
        #pragma unroll
        for (int i = 0; i < 16; i++) acc[i] = 0.f;
        for (int d = 0; d < 64; d++) {
            float qd = Qt[d][t];
            #pragma unroll
            for (int i = 0; i < 16; i++) acc[i] += qd * KV[s0 + i][d];
        }
        #pragma unroll
        for (int i = 0; i < 16; i++) P[t][s0 + i] = acc[i];
    }
    __syncthreads();

    // waves 0-2: reload KV with V; wave 3: compute den[t]
    if (wv == 3) {
        int t = lane;
        const float* zg = zp + (size_t)(b*16 + c) * 64;
        float acc = 0.f;
        for (int d = 0; d < 64; d++) acc += Qt[d][t] * zg[d];
        for (int s = 0; s < 64; s++) acc += (s <= t) ? P[t][s] : 0.f;
        den[t] = acc;
    } else {
        for (int i = tid; i < 1024; i += 192)
            ((float4*)KV)[i] = ((const float4*)Vg)[i];
    }
    __syncthreads();

    // output: thread (e=lane, t in wave's 16)
    {
        int e = lane, t0 = wv * 16;
        const float* Sg = Sp + (size_t)(b*16 + c) * 4096;
        float num[16];
        #pragma unroll
        for (int i = 0; i < 16; i++) num[i] = 0.f;
        for (int d = 0; d < 64; d++) {
            float sde = Sg[d*64 + e];
            #pragma unroll
            for (int i = 0; i < 16; i++) num[i] += Qt[d][t0 + i] * sde;
        }
        for (int i = 0; i < 16; i++) {
            int t = t0 + i;
            float acc = num[i];
            for (int s = 0; s <= t; s++) acc += P[t][s] * KV[s][e];
            num[i] = acc;
        }
        int nb = b >> 4, h = b & 15;
        #pragma unroll
        for (int i = 0; i < 16; i++) {
            int t = t0 + i;
            int l = c*64 + t;
            attn[(size_t)(l*2 + nb) * 1024 + h*64 + e] = num[i] / (den[t] + EPS);
        }
    }
}

// ---------------------------------------------------------------------------
extern "C" void kernel_launch(void* const* d_in, const int* in_sizes, int n_in,
                              void* d_out, int out_size, void* d_ws, size_t ws_size,
                              hipStream_t stream) {
    const float* query = (const float*)d_in[0];
    const float* key_  = (const float*)d_in[1];
    const float* value = (const float*)d_in[2];
    const float* Wq = (const float*)d_in[3];
    const float* bq = (const float*)d_in[4];
    const float* Wk = (const float*)d_in[5];
    const float* bk = (const float*)d_in[6];
    const float* Wv = (const float*)d_in[7];
    const float* bv = (const float*)d_in[8];
    const float* Wo = (const float*)d_in[9];
    const float* bo = (const float*)d_in[10];
    float* out = (float*)d_out;

    // workspace layout (floats): qh, kh, vh (2M each), Sc (2M), zc (32K), attn (2M)
    float* ws = (float*)d_ws;
    float* qh   = ws;
    float* kh   = qh + 2097152;
    float* vh   = kh + 2097152;
    float* Sc   = vh + 2097152;
    float* zc   = Sc + 2097152;
    float* attn = zc + 32768;
    // total: 10,518,528 floats = ~42.1 MB (must fit in ws_size)

    dim3 gGemm(16, 32);  // (N/64, M/64)
    gemm_bt<1><<<gGemm, 256, 0, stream>>>(query, Wq, bq, qh);
    gemm_bt<1><<<gGemm, 256, 0, stream>>>(key_,  Wk, bk, kh);
    gemm_bt<2><<<gGemm, 256, 0, stream>>>(value, Wv, bv, vh);

    chunk_sums<<<dim3(16, 32), 256, 0, stream>>>(kh, vh, Sc, zc);
    prefix_chunks<<<32, 256, 0, stream>>>(Sc, zc);
    attn_chunk<<<dim3(16, 32), 256, 0, stream>>>(qh, kh, vh, Sc, zc, attn);

    gemm_bt<0><<<gGemm, 256, 0, stream>>>(attn, Wo, bo, out);
}

// Round 2
// 129.887 us; speedup vs baseline: 2.6986x; 2.6986x over previous
//
#include <hip/hip_runtime.h>
#include <cmath>

// L=1024, N=2, E=1024, H=16, d=64, B*H=32 heads, chunk C=64, NC=16 chunks
// head layout: [b=32][l=1024][d=64]; attn rows m = l*2 + n_batch

#define EPS 1e-6f

typedef short bf16x8 __attribute__((ext_vector_type(8)));
typedef float f32x4 __attribute__((ext_vector_type(4)));

__device__ __forceinline__ float b2f(ushort u) {
    union { unsigned u32; float f; } x; x.u32 = ((unsigned)u) << 16; return x.f;
}
__device__ __forceinline__ ushort f2b(float f) {
    union { float f; unsigned u; } x; x.f = f;
    unsigned r = (x.u + 0x7fffu + ((x.u >> 16) & 1u)) >> 16;
    return (ushort)r;
}

// async global->LDS, 16B per lane; LDS dest must be wave-uniform base (+lane*16 by HW)
__device__ __forceinline__ void gload16(const void* g, void* l) {
    __builtin_amdgcn_global_load_lds(
        (__attribute__((address_space(1))) void*)(uintptr_t)g,
        (__attribute__((address_space(3))) void*)l,
        16, 0, 0);
}

// ---------------------------------------------------------------------------
// bf16 MFMA GEMM mainloop: C[m][n] = sum_k A[m][k]*B[n][k]
// M-tile 128, N-tile 128, BK=32, 256 threads (4 waves, 2x2 wave grid, 64x64/wave)
// LDS: As/Bs [2][128][32] bf16, double-buffered, global_load_lds staging.
// ---------------------------------------------------------------------------
__device__ __forceinline__ void gemm_mainloop(const ushort* __restrict__ A,
                                              const ushort* __restrict__ B,
                                              int brow, int bcol,
                                              ushort* As, ushort* Bs,
                                              f32x4 acc[4][4]) {
    const int K = 1024;
    int tid = threadIdx.x;
    int w = tid >> 6, lane = tid & 63;
    int wr = w >> 1, wc = w & 1;

    // staging: wave w covers tile rows [w*32, w*32+32), 2 insts of 1KB each
    int srow = w * 32 + (lane >> 2);   // row for j=0 inst
    int ske  = (lane & 3) * 8;         // k-element offset (8 bf16 = 16B)
    const ushort* Ag = A + (size_t)(brow + srow) * K + ske;
    const ushort* Bg = B + (size_t)(bcol + srow) * K + ske;
    int lofs = (w * 32) * 32;          // wave-uniform LDS element offset

    // fragment read pattern (16x16x32 bf16): lane holds row (lane&15), k (lane>>4)*8..+8
    int fr = lane & 15;
    int fk = (lane >> 4) * 8;

    #pragma unroll
    for (int m = 0; m < 4; m++)
        #pragma unroll
        for (int n = 0; n < 4; n++)
            acc[m][n] = (f32x4){0.f, 0.f, 0.f, 0.f};

    // prologue: stage tile t=0 into buffer 0
    #pragma unroll
    for (int j = 0; j < 2; j++) {
        gload16(Ag + (size_t)j * 16 * K, As + lofs + j * 16 * 32);
        gload16(Bg + (size_t)j * 16 * K, Bs + lofs + j * 16 * 32);
    }
    __syncthreads();   // compiler emits vmcnt(0) drain before s_barrier

    int cur = 0;
    for (int t = 0; t < 32; ++t) {
        if (t + 1 < 32) {  // stage next tile into other buffer; overlaps with MFMA below
            int nb = cur ^ 1;
            int k0 = (t + 1) * 32;
            #pragma unroll
            for (int j = 0; j < 2; j++) {
                gload16(Ag + k0 + (size_t)j * 16 * K, As + nb * 4096 + lofs + j * 16 * 32);
                gload16(Bg + k0 + (size_t)j * 16 * K, Bs + nb * 4096 + lofs + j * 16 * 32);
            }
        }
        const ushort* Ac = As + cur * 4096;
        const ushort* Bc = Bs + cur * 4096;
        bf16x8 af[4], bfr[4];
        #pragma unroll
        for (int m = 0; m < 4; m++)
            af[m] = *(const bf16x8*)&Ac[(wr * 64 + m * 16 + fr) * 32 + fk];
        #pragma unroll
        for (int n = 0; n < 4; n++)
            bfr[n] = *(const bf16x8*)&Bc[(wc * 64 + n * 16 + fr) * 32 + fk];
        #pragma unroll
        for (int m = 0; m < 4; m++)
            #pragma unroll
            for (int n = 0; n < 4; n++)
                acc[m][n] = __builtin_amdgcn_mfma_f32_16x16x32_bf16(af[m], bfr[n], acc[m][n], 0, 0, 0);
        __syncthreads();   // drains stage(t+1) vmcnt + all lds reads of buf cur
        cur ^= 1;
    }
}

// proj GEMMs: z=0 q(phi), z=1 k(phi), z=2 v(no phi); bf16 head-layout out
__global__ __launch_bounds__(256) void gemm_proj(
    const ushort* __restrict__ Aq, const ushort* __restrict__ Ak, const ushort* __restrict__ Av,
    const ushort* __restrict__ Bq, const ushort* __restrict__ Bk, const ushort* __restrict__ Bv,
    const float* __restrict__ bq, const float* __restrict__ bk, const float* __restrict__ bv,
    ushort* __restrict__ oq, ushort* __restrict__ ok, ushort* __restrict__ ov) {
    __shared__ ushort As[8192], Bs[8192];
    int z = blockIdx.z;
    const ushort* A = (z == 0) ? Aq : (z == 1) ? Ak : Av;
    const ushort* B = (z == 0) ? Bq : (z == 1) ? Bk : Bv;
    const float* bias = (z == 0) ? bq : (z == 1) ? bk : bv;
    ushort* out = (z == 0) ? oq : (z == 1) ? ok : ov;
    bool phi = (z != 2);
    int brow = blockIdx.y * 128, bcol = blockIdx.x * 128;
    f32x4 acc[4][4];
    gemm_mainloop(A, B, brow, bcol, As, Bs, acc);
    int tid = threadIdx.x, w = tid >> 6, lane = tid & 63;
    int wr = w >> 1, wc = w & 1;
    #pragma unroll
    for (int m = 0; m < 4; m++)
        #pragma unroll
        for (int n = 0; n < 4; n++)
            #pragma unroll
            for (int r = 0; r < 4; r++) {
                int grow = brow + wr * 64 + m * 16 + (lane >> 4) * 4 + r;
                int gcol = bcol + wc * 64 + n * 16 + (lane & 15);
                float v = acc[m][n][r] + bias[gcol];
                if (phi) v = (v > 0.f) ? v + 1.f : __expf(v);
                int l = grow >> 1, nb2 = grow & 1, h = gcol >> 6, dd = gcol & 63;
                out[(size_t)((nb2 * 16 + h) * 1024 + l) * 64 + dd] = f2b(v);
            }
}

// final GEMM: attn(bf16) @ Wo^T + bo -> f32 d_out
__global__ __launch_bounds__(256) void gemm_out(const ushort* __restrict__ A,
                                                const ushort* __restrict__ B,
                                                const float* __restrict__ bias,
                                                float* __restrict__ out) {
    __shared__ ushort As[8192], Bs[8192];
    int brow = blockIdx.y * 128, bcol = blockIdx.x * 128;
    f32x4 acc[4][4];
    gemm_mainloop(A, B, brow, bcol, As, Bs, acc);
    int tid = threadIdx.x, w = tid >> 6, lane = tid & 63;
    int wr = w >> 1, wc = w & 1;
    #pragma unroll
    for (int m = 0; m < 4; m++)
        #pragma unroll
        for (int n = 0; n < 4; n++)
            #pragma unroll
            for (int r = 0; r < 4; r++) {
                int grow = brow + wr * 64 + m * 16 + (lane >> 4) * 4 + r;
                int gcol = bcol + wc * 64 + n * 16 + (lane & 15);
                out[(size_t)grow * 1024 + gcol] = acc[m][n][r] + bias[gcol];
            }
}

// ---------------------------------------------------------------------------
// f32 -> bf16 casts
// ---------------------------------------------------------------------------
__global__ __launch_bounds__(256) void cast_qkv(const float* __restrict__ a, const float* __restrict__ b,
                                                const float* __restrict__ c,
                                                ushort* __restrict__ oa, ushort* __restrict__ ob,
                                                ushort* __restrict__ oc) {
    const float* in = (blockIdx.z == 0) ? a : (blockIdx.z == 1) ? b : c;
    ushort* out = (blockIdx.z == 0) ? oa : (blockIdx.z == 1) ? ob : oc;
    int i = blockIdx.x * 256 + threadIdx.x;
    float4 f = ((const float4*)in)[i];
    ushort4 o; o.x = f2b(f.x); o.y = f2b(f.y); o.z = f2b(f.z); o.w = f2b(f.w);
    ((ushort4*)out)[i] = o;
}

__global__ __launch_bounds__(256) void cast_w(const float* __restrict__ a, const float* __restrict__ b,
                                              const float* __restrict__ c, const float* __restrict__ d,
                                              ushort* __restrict__ oa, ushort* __restrict__ ob,
                                              ushort* __restrict__ oc, ushort* __restrict__ od) {
    const float* in = (blockIdx.z == 0) ? a : (blockIdx.z == 1) ? b : (blockIdx.z == 2) ? c : d;
    ushort* out = (blockIdx.z == 0) ? oa : (blockIdx.z == 1) ? ob : (blockIdx.z == 2) ? oc : od;
    int i = blockIdx.x * 256 + threadIdx.x;
    float4 f = ((const float4*)in)[i];
    ushort4 o; o.x = f2b(f.x); o.y = f2b(f.y); o.z = f2b(f.z); o.w = f2b(f.w);
    ((ushort4*)out)[i] = o;
}

// ---------------------------------------------------------------------------
// Per-(head, chunk) KV sums: Sc[b][c][d][e] = sum_s k[s][d]*v[s][e]; zc = sum k
// ---------------------------------------------------------------------------
__global__ __launch_bounds__(256) void chunk_sums(const ushort* __restrict__ kh,
                                                  const ushort* __restrict__ vh,
                                                  float* __restrict__ Sc,
                                                  float* __restrict__ zc) {
    int c = blockIdx.x, b = blockIdx.y, tid = threadIdx.x;
    __shared__ float Kl[64][64];
    __shared__ float Vl[64][64];
    const ushort* Kg = kh + (size_t)(b * 1024 + c * 64) * 64;
    const ushort* Vg = vh + (size_t)(b * 1024 + c * 64) * 64;
    for (int i = tid; i < 1024; i += 256) {
        ushort4 k4 = ((const ushort4*)Kg)[i];
        ushort4 v4 = ((const ushort4*)Vg)[i];
        ((float4*)Kl)[i] = make_float4(b2f(k4.x), b2f(k4.y), b2f(k4.z), b2f(k4.w));
        ((float4*)Vl)[i] = make_float4(b2f(v4.x), b2f(v4.y), b2f(v4.z), b2f(v4.w));
    }
    __syncthreads();
    int e = tid & 63, d0 = (tid >> 6) * 16;
    float s[16] = {};
    for (int ss = 0; ss < 64; ss++) {
        float ve = Vl[ss][e];
        #pragma unroll
        for (int i = 0; i < 16; i++) s[i] += Kl[ss][d0 + i] * ve;
    }
    float* So = Sc + (size_t)(b * 16 + c) * 4096;
    #pragma unroll
    for (int i = 0; i < 16; i++) So[(d0 + i) * 64 + e] = s[i];
    if (tid < 64) {
        float z = 0.f;
        for (int ss = 0; ss < 64; ss++) z += Kl[ss][tid];
        zc[(size_t)(b * 16 + c) * 64 + tid] = z;
    }
}

__global__ __launch_bounds__(256) void prefix_chunks(float* __restrict__ Sc,
                                                     float* __restrict__ zc) {
    int b = blockIdx.x, tid = threadIdx.x;
    size_t base = (size_t)b * 16 * 4096 + (size_t)tid * 16;
    float run[16] = {};
    for (int c = 0; c < 16; c++) {
        float* p = Sc + base + (size_t)c * 4096;
        #pragma unroll
        for (int i = 0; i < 16; i++) {
            float t = p[i];
            p[i] = run[i];
            run[i] += t;
        }
    }
    if (tid < 64) {
        float rz = 0.f;
        for (int c = 0; c < 16; c++) {
            size_t idx = ((size_t)b * 16 + c) * 64 + tid;
            float t = zc[idx];
            zc[idx] = rz;
            rz += t;
        }
    }
}

// ---------------------------------------------------------------------------
// Per-(head, chunk) attention -> bf16 attn rows
// ---------------------------------------------------------------------------
__global__ __launch_bounds__(256) void attn_chunk(const ushort* __restrict__ qh,
                                                  const ushort* __restrict__ kh,
                                                  const ushort* __restrict__ vh,
                                                  const float* __restrict__ Sp,
                                                  const float* __restrict__ zp,
                                                  ushort* __restrict__ attn) {
    int c = blockIdx.x, b = blockIdx.y, tid = threadIdx.x;
    int lane = tid & 63, wv = tid >> 6;
    __shared__ float Qt[64][64];   // Qt[d][t]
    __shared__ float KV[64][64];   // K rows, then V rows
    __shared__ float P[64][65];
    __shared__ float den[64];

    const ushort* Qg = qh + (size_t)(b * 1024 + c * 64) * 64;
    const ushort* Kg = kh + (size_t)(b * 1024 + c * 64) * 64;
    const ushort* Vg = vh + (size_t)(b * 1024 + c * 64) * 64;

    for (int i = tid; i < 1024; i += 256) {
        int t = i >> 4;
        int d4 = (i & 15) << 2;
        ushort4 q4 = ((const ushort4*)Qg)[i];
        Qt[d4 + 0][t] = b2f(q4.x); Qt[d4 + 1][t] = b2f(q4.y);
        Qt[d4 + 2][t] = b2f(q4.z); Qt[d4 + 3][t] = b2f(q4.w);
        ushort4 k4 = ((const ushort4*)Kg)[i];
        *(float4*)&KV[t][d4] = make_float4(b2f(k4.x), b2f(k4.y), b2f(k4.z), b2f(k4.w));
    }
    __syncthreads();

    {   // P[t][s] for this wave's 16 s values
        int t = lane, s0 = wv * 16;
        float accp[16];
        #pragma unroll
        for (int i = 0; i < 16; i++) accp[i] = 0.f;
        for (int d = 0; d < 64; d++) {
            float qd = Qt[d][t];
            #pragma unroll
            for (int i = 0; i < 16; i++) accp[i] += qd * KV[s0 + i][d];
        }
        #pragma unroll
        for (int i = 0; i < 16; i++) P[t][s0 + i] = accp[i];
    }
    __syncthreads();

    if (wv == 3) {
        int t = lane;
        const float* zg = zp + (size_t)(b * 16 + c) * 64;
        float acc = 0.f;
        for (int d = 0; d < 64; d++) acc += Qt[d][t] * zg[d];
        for (int s = 0; s < 64; s++) acc += (s <= t) ? P[t][s] : 0.f;
        den[t] = acc;
    } else {
        for (int i = tid; i < 1024; i += 192) {
            ushort4 v4 = ((const ushort4*)Vg)[i];
            ((float4*)KV)[i] = make_float4(b2f(v4.x), b2f(v4.y), b2f(v4.z), b2f(v4.w));
        }
    }
    __syncthreads();

    {
        int e = lane, t0 = wv * 16;
        const float* Sg = Sp + (size_t)(b * 16 + c) * 4096;
        float num[16];
        #pragma unroll
        for (int i = 0; i < 16; i++) num[i] = 0.f;
        for (int d = 0; d < 64; d++) {
            float sde = Sg[d * 64 + e];
            #pragma unroll
            for (int i = 0; i < 16; i++) num[i] += Qt[d][t0 + i] * sde;
        }
        for (int i = 0; i < 16; i++) {
            int t = t0 + i;
            float acc = num[i];
            for (int s = 0; s <= t; s++) acc += P[t][s] * KV[s][e];
            num[i] = acc;
        }
        int nb = b >> 4, h = b & 15;
        #pragma unroll
        for (int i = 0; i < 16; i++) {
            int t = t0 + i;
            int l = c * 64 + t;
            attn[(size_t)(l * 2 + nb) * 1024 + h * 64 + e] = f2b(num[i] / (den[t] + EPS));
        }
    }
}

// ---------------------------------------------------------------------------
extern "C" void kernel_launch(void* const* d_in, const int* in_sizes, int n_in,
                              void* d_out, int out_size, void* d_ws, size_t ws_size,
                              hipStream_t stream) {
    const float* query = (const float*)d_in[0];
    const float* key_  = (const float*)d_in[1];
    const float* value = (const float*)d_in[2];
    const float* Wq = (const float*)d_in[3];
    const float* bq = (const float*)d_in[4];
    const float* Wk = (const float*)d_in[5];
    const float* bk = (const float*)d_in[6];
    const float* Wv = (const float*)d_in[7];
    const float* bv = (const float*)d_in[8];
    const float* Wo = (const float*)d_in[9];
    const float* bo = (const float*)d_in[10];

    // workspace: bf16 A-copies (12MB) + bf16 weights (8MB) + bf16 heads (12MB)
    //          + f32 Sc (8MB) + f32 zc (128KB); attn aliases qbuf. Total ~40.1MB.
    ushort* qbuf = (ushort*)d_ws;
    ushort* kbuf = qbuf + 2097152;
    ushort* vbuf = kbuf + 2097152;
    ushort* wqb  = vbuf + 2097152;
    ushort* wkb  = wqb + 1048576;
    ushort* wvb  = wkb + 1048576;
    ushort* wob  = wvb + 1048576;
    ushort* qh   = wob + 1048576;
    ushort* kh   = qh + 2097152;
    ushort* vh   = kh + 2097152;
    float*  Sc   = (float*)(vh + 2097152);
    float*  zc   = Sc + 2097152;
    ushort* attn = qbuf;  // qbuf dead after proj GEMM

    cast_qkv<<<dim3(2048, 1, 3), 256, 0, stream>>>(query, key_, value, qbuf, kbuf, vbuf);
    cast_w<<<dim3(1024, 1, 4), 256, 0, stream>>>(Wq, Wk, Wv, Wo, wqb, wkb, wvb, wob);

    gemm_proj<<<dim3(8, 16, 3), 256, 0, stream>>>(qbuf, kbuf, vbuf, wqb, wkb, wvb,
                                                  bq, bk, bv, qh, kh, vh);

    chunk_sums<<<dim3(16, 32), 256, 0, stream>>>(kh, vh, Sc, zc);
    prefix_chunks<<<32, 256, 0, stream>>>(Sc, zc);
    attn_chunk<<<dim3(16, 32), 256, 0, stream>>>(qh, kh, vh, Sc, zc, attn);

    gemm_out<<<dim3(8, 16), 256, 0, stream>>>(attn, wob, bo, (float*)d_out);
}

// Round 3
// 115.369 us; speedup vs baseline: 3.0382x; 1.1258x over previous
//
#include <hip/hip_runtime.h>
#include <cmath>

// L=1024, N=2, E=1024, H=16, d=64, B*H=32 heads, chunk C=64, NC=16 chunks
// head layout: [b=32][l=1024][d=64]; attn rows m = l*2 + n_batch

#define EPS 1e-6f

typedef short bf16x8 __attribute__((ext_vector_type(8)));
typedef float f32x4 __attribute__((ext_vector_type(4)));

__device__ __forceinline__ float b2f(ushort u) {
    union { unsigned u32; float f; } x; x.u32 = ((unsigned)u) << 16; return x.f;
}
__device__ __forceinline__ ushort f2b(float f) {
    union { float f; unsigned u; } x; x.f = f;
    unsigned r = (x.u + 0x7fffu + ((x.u >> 16) & 1u)) >> 16;
    return (ushort)r;
}

__device__ __forceinline__ void gload16(const void* g, void* l) {
    __builtin_amdgcn_global_load_lds(
        (__attribute__((address_space(1))) void*)(uintptr_t)g,
        (__attribute__((address_space(3))) void*)l,
        16, 0, 0);
}

// ---------------------------------------------------------------------------
// bf16 MFMA GEMM mainloop: C[m][n] = sum_k A[m][k]*B[n][k], K=1024
// Block tile 64(M) x 128(N), BK=32, 256 threads = 4 waves (2x2), 32x64/wave.
// LDS per buffer: A 64x32 (4KB) + B 128x32 (8KB); double-buffered = 24KB.
// XOR swizzle (key=(row>>1)&3 on 16B slots) applied BOTH sides:
//   stage: global source slot pre-swizzled (LDS written linearly by HW)
//   read:  ds_read slot XOR'd back  -> conflict-free (2 lanes/bank)
// ---------------------------------------------------------------------------
__device__ __forceinline__ void gemm_mainloop(const ushort* __restrict__ A,
                                              const ushort* __restrict__ B,
                                              int brow, int bcol,
                                              ushort* Sh,   // [2][6144]
                                              f32x4 acc[2][4]) {
    const int K = 1024;
    int tid = threadIdx.x;
    int w = tid >> 6, lane = tid & 63;
    int wr = w >> 1, wc = w & 1;

    // staging addresses (per-thread global, wave-uniform LDS)
    int sr = tid >> 2;                                  // local row 0..63
    int ss = ((tid & 3) ^ ((sr >> 1) & 3)) * 8;         // swizzled k-elem offset
    const ushort* Ag = A + (size_t)(brow + sr) * K + ss;
    const ushort* Bg = B + (size_t)(bcol + sr) * K + ss; // +64 rows for inst j=1 (same key)
    int awofs = w * 512;                                 // wave base in A region (elems)

    // fragment read offsets
    int fr = lane & 15, hi = lane >> 4;
    int ea[2], eb[4];
    #pragma unroll
    for (int m = 0; m < 2; m++) {
        int row = wr * 32 + m * 16 + fr;
        ea[m] = row * 32 + ((hi ^ ((row >> 1) & 3)) * 8);
    }
    #pragma unroll
    for (int n = 0; n < 4; n++) {
        int row = wc * 64 + n * 16 + fr;
        eb[n] = row * 32 + ((hi ^ ((row >> 1) & 3)) * 8);
    }

    #pragma unroll
    for (int m = 0; m < 2; m++)
        #pragma unroll
        for (int n = 0; n < 4; n++)
            acc[m][n] = (f32x4){0.f, 0.f, 0.f, 0.f};

    // prologue: stage tile 0 into buffer 0
    gload16(Ag, Sh + awofs);
    gload16(Bg, Sh + 2048 + awofs);
    gload16(Bg + (size_t)64 * K, Sh + 2048 + 2048 + awofs);
    __syncthreads();

    int cur = 0;
    for (int t = 0; t < 32; ++t) {
        if (t + 1 < 32) {
            int k0 = (t + 1) * 32;
            ushort* Sn = Sh + (cur ^ 1) * 6144;
            gload16(Ag + k0, Sn + awofs);
            gload16(Bg + k0, Sn + 2048 + awofs);
            gload16(Bg + k0 + (size_t)64 * K, Sn + 2048 + 2048 + awofs);
        }
        const ushort* Ac = Sh + cur * 6144;
        const ushort* Bc = Ac + 2048;
        bf16x8 af[2], bf[4];
        #pragma unroll
        for (int m = 0; m < 2; m++) af[m] = *(const bf16x8*)&Ac[ea[m]];
        #pragma unroll
        for (int n = 0; n < 4; n++) bf[n] = *(const bf16x8*)&Bc[eb[n]];
        #pragma unroll
        for (int m = 0; m < 2; m++)
            #pragma unroll
            for (int n = 0; n < 4; n++)
                acc[m][n] = __builtin_amdgcn_mfma_f32_16x16x32_bf16(af[m], bf[n], acc[m][n], 0, 0, 0);
        __syncthreads();
        cur ^= 1;
    }
}

// proj GEMMs: z=0 q(phi), z=1 k(phi), z=2 v(no phi); bf16 head-layout out
__global__ __launch_bounds__(256) void gemm_proj(
    const ushort* __restrict__ Aq, const ushort* __restrict__ Ak, const ushort* __restrict__ Av,
    const ushort* __restrict__ Bq, const ushort* __restrict__ Bk, const ushort* __restrict__ Bv,
    const float* __restrict__ bq, const float* __restrict__ bk, const float* __restrict__ bv,
    ushort* __restrict__ oq, ushort* __restrict__ ok, ushort* __restrict__ ov) {
    __shared__ ushort Sh[2 * 6144];
    int z = blockIdx.z;
    const ushort* A = (z == 0) ? Aq : (z == 1) ? Ak : Av;
    const ushort* B = (z == 0) ? Bq : (z == 1) ? Bk : Bv;
    const float* bias = (z == 0) ? bq : (z == 1) ? bk : bv;
    ushort* out = (z == 0) ? oq : (z == 1) ? ok : ov;
    bool phi = (z != 2);
    int brow = blockIdx.y * 64, bcol = blockIdx.x * 128;
    f32x4 acc[2][4];
    gemm_mainloop(A, B, brow, bcol, Sh, acc);
    int tid = threadIdx.x, w = tid >> 6, lane = tid & 63;
    int wr = w >> 1, wc = w & 1;
    int fr = lane & 15, hi = lane >> 4;
    #pragma unroll
    for (int m = 0; m < 2; m++)
        #pragma unroll
        for (int n = 0; n < 4; n++)
            #pragma unroll
            for (int r = 0; r < 4; r++) {
                int grow = brow + wr * 32 + m * 16 + hi * 4 + r;
                int gcol = bcol + wc * 64 + n * 16 + fr;
                float v = acc[m][n][r] + bias[gcol];
                if (phi) v = (v > 0.f) ? v + 1.f : __expf(v);
                int l = grow >> 1, nb2 = grow & 1, h = gcol >> 6, dd = gcol & 63;
                out[(size_t)((nb2 * 16 + h) * 1024 + l) * 64 + dd] = f2b(v);
            }
}

// final GEMM: attn(bf16) @ Wo^T + bo -> f32 d_out
__global__ __launch_bounds__(256) void gemm_out(const ushort* __restrict__ A,
                                                const ushort* __restrict__ B,
                                                const float* __restrict__ bias,
                                                float* __restrict__ out) {
    __shared__ ushort Sh[2 * 6144];
    int brow = blockIdx.y * 64, bcol = blockIdx.x * 128;
    f32x4 acc[2][4];
    gemm_mainloop(A, B, brow, bcol, Sh, acc);
    int tid = threadIdx.x, w = tid >> 6, lane = tid & 63;
    int wr = w >> 1, wc = w & 1;
    int fr = lane & 15, hi = lane >> 4;
    #pragma unroll
    for (int m = 0; m < 2; m++)
        #pragma unroll
        for (int n = 0; n < 4; n++)
            #pragma unroll
            for (int r = 0; r < 4; r++) {
                int grow = brow + wr * 32 + m * 16 + hi * 4 + r;
                int gcol = bcol + wc * 64 + n * 16 + fr;
                out[(size_t)grow * 1024 + gcol] = acc[m][n][r] + bias[gcol];
            }
}

// ---------------------------------------------------------------------------
// merged f32 -> bf16 cast: z 0..2 -> q,k,v (2M elems); z 3..6 -> Wq,Wk,Wv,Wo (1M)
// ---------------------------------------------------------------------------
__global__ __launch_bounds__(256) void cast_all(
    const float* __restrict__ i0, const float* __restrict__ i1, const float* __restrict__ i2,
    const float* __restrict__ i3, const float* __restrict__ i4, const float* __restrict__ i5,
    const float* __restrict__ i6,
    ushort* __restrict__ o0, ushort* __restrict__ o1, ushort* __restrict__ o2,
    ushort* __restrict__ o3, ushort* __restrict__ o4, ushort* __restrict__ o5,
    ushort* __restrict__ o6) {
    int z = blockIdx.z;
    const float* in = (z == 0) ? i0 : (z == 1) ? i1 : (z == 2) ? i2 :
                      (z == 3) ? i3 : (z == 4) ? i4 : (z == 5) ? i5 : i6;
    ushort* out = (z == 0) ? o0 : (z == 1) ? o1 : (z == 2) ? o2 :
                  (z == 3) ? o3 : (z == 4) ? o4 : (z == 5) ? o5 : o6;
    int n4 = (z < 3) ? 524288 : 262144;
    int i = blockIdx.x * 256 + threadIdx.x;
    if (i < n4) {
        float4 f = ((const float4*)in)[i];
        ushort4 o; o.x = f2b(f.x); o.y = f2b(f.y); o.z = f2b(f.z); o.w = f2b(f.w);
        ((ushort4*)out)[i] = o;
    }
}

// ---------------------------------------------------------------------------
// Per-(head, chunk) KV sums: Sc[b][c][d][e] = sum_s k[s][d]*v[s][e]; zc = sum k
// ---------------------------------------------------------------------------
__global__ __launch_bounds__(256) void chunk_sums(const ushort* __restrict__ kh,
                                                  const ushort* __restrict__ vh,
                                                  float* __restrict__ Sc,
                                                  float* __restrict__ zc) {
    int c = blockIdx.x, b = blockIdx.y, tid = threadIdx.x;
    __shared__ float Kl[64][64];
    __shared__ float Vl[64][64];
    const ushort* Kg = kh + (size_t)(b * 1024 + c * 64) * 64;
    const ushort* Vg = vh + (size_t)(b * 1024 + c * 64) * 64;
    for (int i = tid; i < 1024; i += 256) {
        ushort4 k4 = ((const ushort4*)Kg)[i];
        ushort4 v4 = ((const ushort4*)Vg)[i];
        ((float4*)Kl)[i] = make_float4(b2f(k4.x), b2f(k4.y), b2f(k4.z), b2f(k4.w));
        ((float4*)Vl)[i] = make_float4(b2f(v4.x), b2f(v4.y), b2f(v4.z), b2f(v4.w));
    }
    __syncthreads();
    int e = tid & 63, d0 = (tid >> 6) * 16;
    float s[16] = {};
    for (int ss = 0; ss < 64; ss++) {
        float ve = Vl[ss][e];
        #pragma unroll
        for (int i = 0; i < 16; i++) s[i] += Kl[ss][d0 + i] * ve;
    }
    float* So = Sc + (size_t)(b * 16 + c) * 4096;
    #pragma unroll
    for (int i = 0; i < 16; i++) So[(d0 + i) * 64 + e] = s[i];
    if (tid < 64) {
        float z = 0.f;
        for (int ss = 0; ss < 64; ss++) z += Kl[ss][tid];
        zc[(size_t)(b * 16 + c) * 64 + tid] = z;
    }
}

__global__ __launch_bounds__(256) void prefix_chunks(float* __restrict__ Sc,
                                                     float* __restrict__ zc) {
    int b = blockIdx.x, tid = threadIdx.x;
    size_t base = (size_t)b * 16 * 4096 + (size_t)tid * 16;
    float run[16] = {};
    for (int c = 0; c < 16; c++) {
        float* p = Sc + base + (size_t)c * 4096;
        #pragma unroll
        for (int i = 0; i < 16; i++) {
            float t = p[i];
            p[i] = run[i];
            run[i] += t;
        }
    }
    if (tid < 64) {
        float rz = 0.f;
        for (int c = 0; c < 16; c++) {
            size_t idx = ((size_t)b * 16 + c) * 64 + tid;
            float t = zc[idx];
            zc[idx] = rz;
            rz += t;
        }
    }
}

// ---------------------------------------------------------------------------
// Per-(head, chunk) attention -> bf16 attn rows
// ---------------------------------------------------------------------------
__global__ __launch_bounds__(256) void attn_chunk(const ushort* __restrict__ qh,
                                                  const ushort* __restrict__ kh,
                                                  const ushort* __restrict__ vh,
                                                  const float* __restrict__ Sp,
                                                  const float* __restrict__ zp,
                                                  ushort* __restrict__ attn) {
    int c = blockIdx.x, b = blockIdx.y, tid = threadIdx.x;
    int lane = tid & 63, wv = tid >> 6;
    __shared__ float Qt[64][64];   // Qt[d][t]
    __shared__ float KV[64][64];   // K rows, then V rows
    __shared__ float P[64][65];
    __shared__ float den[64];

    const ushort* Qg = qh + (size_t)(b * 1024 + c * 64) * 64;
    const ushort* Kg = kh + (size_t)(b * 1024 + c * 64) * 64;
    const ushort* Vg = vh + (size_t)(b * 1024 + c * 64) * 64;

    for (int i = tid; i < 1024; i += 256) {
        int t = i >> 4;
        int d4 = (i & 15) << 2;
        ushort4 q4 = ((const ushort4*)Qg)[i];
        Qt[d4 + 0][t] = b2f(q4.x); Qt[d4 + 1][t] = b2f(q4.y);
        Qt[d4 + 2][t] = b2f(q4.z); Qt[d4 + 3][t] = b2f(q4.w);
        ushort4 k4 = ((const ushort4*)Kg)[i];
        *(float4*)&KV[t][d4] = make_float4(b2f(k4.x), b2f(k4.y), b2f(k4.z), b2f(k4.w));
    }
    __syncthreads();

    {   // P[t][s] for this wave's 16 s values
        int t = lane, s0 = wv * 16;
        float accp[16];
        #pragma unroll
        for (int i = 0; i < 16; i++) accp[i] = 0.f;
        for (int d = 0; d < 64; d++) {
            float qd = Qt[d][t];
            #pragma unroll
            for (int i = 0; i < 16; i++) accp[i] += qd * KV[s0 + i][d];
        }
        #pragma unroll
        for (int i = 0; i < 16; i++) P[t][s0 + i] = accp[i];
    }
    __syncthreads();

    if (wv == 3) {
        int t = lane;
        const float* zg = zp + (size_t)(b * 16 + c) * 64;
        float acc = 0.f;
        for (int d = 0; d < 64; d++) acc += Qt[d][t] * zg[d];
        for (int s = 0; s < 64; s++) acc += (s <= t) ? P[t][s] : 0.f;
        den[t] = acc;
    } else {
        for (int i = tid; i < 1024; i += 192) {
            ushort4 v4 = ((const ushort4*)Vg)[i];
            ((float4*)KV)[i] = make_float4(b2f(v4.x), b2f(v4.y), b2f(v4.z), b2f(v4.w));
        }
    }
    __syncthreads();

    {
        int e = lane, t0 = wv * 16;
        const float* Sg = Sp + (size_t)(b * 16 + c) * 4096;
        float num[16];
        #pragma unroll
        for (int i = 0; i < 16; i++) num[i] = 0.f;
        for (int d = 0; d < 64; d++) {
            float sde = Sg[d * 64 + e];
            #pragma unroll
            for (int i = 0; i < 16; i++) num[i] += Qt[d][t0 + i] * sde;
        }
        for (int i = 0; i < 16; i++) {
            int t = t0 + i;
            float acc = num[i];
            for (int s = 0; s <= t; s++) acc += P[t][s] * KV[s][e];
            num[i] = acc;
        }
        int nb = b >> 4, h = b & 15;
        #pragma unroll
        for (int i = 0; i < 16; i++) {
            int t = t0 + i;
            int l = c * 64 + t;
            attn[(size_t)(l * 2 + nb) * 1024 + h * 64 + e] = f2b(num[i] / (den[t] + EPS));
        }
    }
}

// ---------------------------------------------------------------------------
extern "C" void kernel_launch(void* const* d_in, const int* in_sizes, int n_in,
                              void* d_out, int out_size, void* d_ws, size_t ws_size,
                              hipStream_t stream) {
    const float* query = (const float*)d_in[0];
    const float* key_  = (const float*)d_in[1];
    const float* value = (const float*)d_in[2];
    const float* Wq = (const float*)d_in[3];
    const float* bq = (const float*)d_in[4];
    const float* Wk = (const float*)d_in[5];
    const float* bk = (const float*)d_in[6];
    const float* Wv = (const float*)d_in[7];
    const float* bv = (const float*)d_in[8];
    const float* Wo = (const float*)d_in[9];
    const float* bo = (const float*)d_in[10];

    ushort* qbuf = (ushort*)d_ws;
    ushort* kbuf = qbuf + 2097152;
    ushort* vbuf = kbuf + 2097152;
    ushort* wqb  = vbuf + 2097152;
    ushort* wkb  = wqb + 1048576;
    ushort* wvb  = wkb + 1048576;
    ushort* wob  = wvb + 1048576;
    ushort* qh   = wob + 1048576;
    ushort* kh   = qh + 2097152;
    ushort* vh   = kh + 2097152;
    float*  Sc   = (float*)(vh + 2097152);
    float*  zc   = Sc + 2097152;
    ushort* attn = qbuf;  // qbuf dead after proj GEMM

    cast_all<<<dim3(2048, 1, 7), 256, 0, stream>>>(query, key_, value, Wq, Wk, Wv, Wo,
                                                   qbuf, kbuf, vbuf, wqb, wkb, wvb, wob);

    gemm_proj<<<dim3(8, 32, 3), 256, 0, stream>>>(qbuf, kbuf, vbuf, wqb, wkb, wvb,
                                                  bq, bk, bv, qh, kh, vh);

    chunk_sums<<<dim3(16, 32), 256, 0, stream>>>(kh, vh, Sc, zc);
    prefix_chunks<<<32, 256, 0, stream>>>(Sc, zc);
    attn_chunk<<<dim3(16, 32), 256, 0, stream>>>(qh, kh, vh, Sc, zc, attn);

    gemm_out<<<dim3(8, 32), 256, 0, stream>>>(attn, wob, bo, (float*)d_out);
}

// Round 4
// 96.969 us; speedup vs baseline: 3.6147x; 1.1897x over previous
//
#include <hip/hip_runtime.h>
#include <cmath>

// L=1024, N=2, E=1024, H=16, d=64, B*H=32 heads, chunk C=64, NC=16 chunks
// qh/kh: [b=32][l=1024][d=64] bf16 ; vt: [b=32][e=64][l=1024] bf16
// St/Spt: [b][c][e=64][d=64] (S^T, exclusive prefix in Spt) ; zc: [b][c][64] f32
// attn rows m = l*2 + nb, cols h*64+e

#define EPS 1e-6f

typedef short bf16x8 __attribute__((ext_vector_type(8)));
typedef float f32x4 __attribute__((ext_vector_type(4)));

__device__ __forceinline__ float b2f(ushort u) {
    union { unsigned u32; float f; } x; x.u32 = ((unsigned)u) << 16; return x.f;
}
__device__ __forceinline__ ushort f2b(float f) {
    union { float f; unsigned u; } x; x.f = f;
    unsigned r = (x.u + 0x7fffu + ((x.u >> 16) & 1u)) >> 16;
    return (ushort)r;
}
__device__ __forceinline__ void gload16(const void* g, void* l) {
    __builtin_amdgcn_global_load_lds(
        (__attribute__((address_space(1))) void*)(uintptr_t)g,
        (__attribute__((address_space(3))) void*)l,
        16, 0, 0);
}

// ---------------------------------------------------------------------------
// bf16 MFMA GEMM mainloop: C[m][n] = sum_k A[m][k]*B[n][k] (both row-major, K=1024)
// Tile 64(M) x 128(N), BK=32, 128 threads = 2 waves, each wave 64x64 (ratio 2.0).
// LDS/buf: A 64x32 (4KB) + B 128x32 (8KB), double-buffered = 24KB.
// Swizzle key (row>>1)&3 on 16B slots, both sides (pre-swizzled global source).
// ---------------------------------------------------------------------------
__device__ __forceinline__ void gemm_mainloop2(const ushort* __restrict__ A,
                                               const ushort* __restrict__ B,
                                               int brow, int bcol, int kbeg, int nsteps,
                                               ushort* Sh, f32x4 acc[4][4]) {
    const int K = 1024;
    int tid = threadIdx.x;
    int w = tid >> 6, lane = tid & 63;
    int fr = lane & 15, hi = lane >> 4;

    // staging: per thread 2 A-gloads + 4 B-gloads, 16B each
    int srow = lane >> 2;                     // 0..15 within 16-row group
    int ssl  = lane & 3;                      // dest slot
    // A inst j: rows (w*2+j)*16 + srow ; B inst j: rows (w*4+j)*16 + srow
    int arowA = (w * 2) * 16 + srow;          // j=0 row (j=1: +16, same swz key)
    int arowB = (w * 4) * 16 + srow;
    const ushort* Ag = A + (size_t)(brow + arowA) * K + kbeg + ((ssl ^ ((arowA >> 1) & 3)) * 8);
    const ushort* Bg = B + (size_t)(bcol + arowB) * K + kbeg + ((ssl ^ ((arowB >> 1) & 3)) * 8);
    int adst = w * 1024;                      // elem offsets (wave-uniform)
    int bdst = 2048 + w * 2048;

    // fragment offsets: key = (fr>>1)&3 uniform per lane for all frags
    int fkey = (fr >> 1) & 3;
    int ea[4], eb[4];
    #pragma unroll
    for (int m = 0; m < 4; m++) ea[m] = (m * 16 + fr) * 32 + ((hi ^ fkey) * 8);
    #pragma unroll
    for (int n = 0; n < 4; n++) eb[n] = 2048 + (w * 64 + n * 16 + fr) * 32 + ((hi ^ fkey) * 8);

    #pragma unroll
    for (int m = 0; m < 4; m++)
        #pragma unroll
        for (int n = 0; n < 4; n++)
            acc[m][n] = (f32x4){0.f, 0.f, 0.f, 0.f};

    // prologue: stage step 0 into buffer 0
    #pragma unroll
    for (int j = 0; j < 2; j++) gload16(Ag + (size_t)j * 16 * K, Sh + adst + j * 512);
    #pragma unroll
    for (int j = 0; j < 4; j++) gload16(Bg + (size_t)j * 16 * K, Sh + bdst + j * 512);
    __syncthreads();

    int cur = 0;
    for (int t = 0; t < nsteps; ++t) {
        if (t + 1 < nsteps) {
            int k0 = (t + 1) * 32;
            ushort* Sn = Sh + (cur ^ 1) * 6144;
            #pragma unroll
            for (int j = 0; j < 2; j++) gload16(Ag + k0 + (size_t)j * 16 * K, Sn + adst + j * 512);
            #pragma unroll
            for (int j = 0; j < 4; j++) gload16(Bg + k0 + (size_t)j * 16 * K, Sn + bdst + j * 512);
        }
        const ushort* Sc_ = Sh + cur * 6144;
        bf16x8 af[4], bf[4];
        #pragma unroll
        for (int m = 0; m < 4; m++) af[m] = *(const bf16x8*)&Sc_[ea[m]];
        #pragma unroll
        for (int n = 0; n < 4; n++) bf[n] = *(const bf16x8*)&Sc_[eb[n]];
        #pragma unroll
        for (int m = 0; m < 4; m++)
            #pragma unroll
            for (int n = 0; n < 4; n++)
                acc[m][n] = __builtin_amdgcn_mfma_f32_16x16x32_bf16(af[m], bf[n], acc[m][n], 0, 0, 0);
        __syncthreads();
        cur ^= 1;
    }
}

// proj GEMMs: z=0 q(phi)->qh, z=1 k(phi)->kh, z=2 v->vt (transposed head layout)
__global__ __launch_bounds__(128) void gemm_proj(
    const ushort* __restrict__ Aq, const ushort* __restrict__ Ak, const ushort* __restrict__ Av,
    const ushort* __restrict__ Bq, const ushort* __restrict__ Bk, const ushort* __restrict__ Bv,
    const float* __restrict__ bq, const float* __restrict__ bk, const float* __restrict__ bv,
    ushort* __restrict__ oq, ushort* __restrict__ ok, ushort* __restrict__ ov) {
    __shared__ ushort Sh[2 * 6144];
    int z = blockIdx.z;
    const ushort* A = (z == 0) ? Aq : (z == 1) ? Ak : Av;
    const ushort* B = (z == 0) ? Bq : (z == 1) ? Bk : Bv;
    const float* bias = (z == 0) ? bq : (z == 1) ? bk : bv;
    int brow = blockIdx.y * 64, bcol = blockIdx.x * 128;
    f32x4 acc[4][4];
    gemm_mainloop2(A, B, brow, bcol, 0, 32, Sh, acc);
    int tid = threadIdx.x, w = tid >> 6, lane = tid & 63;
    int fr = lane & 15, hi = lane >> 4;
    #pragma unroll
    for (int m = 0; m < 4; m++)
        #pragma unroll
        for (int n = 0; n < 4; n++)
            #pragma unroll
            for (int r = 0; r < 4; r++) {
                int grow = brow + m * 16 + hi * 4 + r;
                int gcol = bcol + w * 64 + n * 16 + fr;
                float v = acc[m][n][r] + bias[gcol];
                int l = grow >> 1, nb2 = grow & 1, h = gcol >> 6, dd = gcol & 63;
                if (z == 2) {
                    ov[(size_t)((nb2 * 16 + h) * 64 + dd) * 1024 + l] = f2b(v);
                } else {
                    v = (v > 0.f) ? v + 1.f : __expf(v);
                    ushort* out = (z == 0) ? oq : ok;
                    out[(size_t)((nb2 * 16 + h) * 1024 + l) * 64 + dd] = f2b(v);
                }
            }
}

// out GEMM, split-K=4: partial[z][m][n] = sum_{k in z-slice} attn[m][k]*Wo[n][k]
__global__ __launch_bounds__(128) void gemm_outk(const ushort* __restrict__ A,
                                                 const ushort* __restrict__ B,
                                                 float* __restrict__ pbuf) {
    __shared__ ushort Sh[2 * 6144];
    int brow = blockIdx.y * 64, bcol = blockIdx.x * 128, z = blockIdx.z;
    f32x4 acc[4][4];
    gemm_mainloop2(A, B, brow, bcol, z * 256, 8, Sh, acc);
    int tid = threadIdx.x, w = tid >> 6, lane = tid & 63;
    int fr = lane & 15, hi = lane >> 4;
    float* out = pbuf + (size_t)z * 2097152;
    #pragma unroll
    for (int m = 0; m < 4; m++)
        #pragma unroll
        for (int n = 0; n < 4; n++)
            #pragma unroll
            for (int r = 0; r < 4; r++) {
                int grow = brow + m * 16 + hi * 4 + r;
                int gcol = bcol + w * 64 + n * 16 + fr;
                out[(size_t)grow * 1024 + gcol] = acc[m][n][r];
            }
}

__global__ __launch_bounds__(256) void reduce_out(const float* __restrict__ p,
                                                  const float* __restrict__ bias,
                                                  float* __restrict__ out) {
    int i = blockIdx.x * 256 + threadIdx.x;      // over 524288 float4s
    float4 a = ((const float4*)p)[i];
    float4 b = ((const float4*)(p + 2097152))[i];
    float4 c = ((const float4*)(p + 4194304))[i];
    float4 d = ((const float4*)(p + 6291456))[i];
    float4 bb = ((const float4*)bias)[i & 255];
    float4 o;
    o.x = a.x + b.x + c.x + d.x + bb.x;
    o.y = a.y + b.y + c.y + d.y + bb.y;
    o.z = a.z + b.z + c.z + d.z + bb.z;
    o.w = a.w + b.w + c.w + d.w + bb.w;
    ((float4*)out)[i] = o;
}

// ---------------------------------------------------------------------------
// merged f32 -> bf16 cast: z 0..2 -> q,k,v (2M elems); z 3..6 -> Wq,Wk,Wv,Wo (1M)
// ---------------------------------------------------------------------------
__global__ __launch_bounds__(256) void cast_all(
    const float* __restrict__ i0, const float* __restrict__ i1, const float* __restrict__ i2,
    const float* __restrict__ i3, const float* __restrict__ i4, const float* __restrict__ i5,
    const float* __restrict__ i6,
    ushort* __restrict__ o0, ushort* __restrict__ o1, ushort* __restrict__ o2,
    ushort* __restrict__ o3, ushort* __restrict__ o4, ushort* __restrict__ o5,
    ushort* __restrict__ o6) {
    int z = blockIdx.z;
    const float* in = (z == 0) ? i0 : (z == 1) ? i1 : (z == 2) ? i2 :
                      (z == 3) ? i3 : (z == 4) ? i4 : (z == 5) ? i5 : i6;
    ushort* out = (z == 0) ? o0 : (z == 1) ? o1 : (z == 2) ? o2 :
                  (z == 3) ? o3 : (z == 4) ? o4 : (z == 5) ? o5 : o6;
    int n4 = (z < 3) ? 524288 : 262144;
    int i = blockIdx.x * 256 + threadIdx.x;
    if (i < n4) {
        float4 f = ((const float4*)in)[i];
        ushort4 o; o.x = f2b(f.x); o.y = f2b(f.y); o.z = f2b(f.z); o.w = f2b(f.w);
        ((ushort4*)out)[i] = o;
    }
}

// ---------------------------------------------------------------------------
// Per-(head, chunk) KV sums, transposed out: St[b][c][e][d] = sum_s v[s][e]*k[s][d]
// zc[b][c][d] = sum_s k[s][d]
// ---------------------------------------------------------------------------
__global__ __launch_bounds__(256) void chunk_sums(const ushort* __restrict__ kh,
                                                  const ushort* __restrict__ vt,
                                                  float* __restrict__ St,
                                                  float* __restrict__ zc) {
    int c = blockIdx.x, b = blockIdx.y, tid = threadIdx.x;
    __shared__ float Kl[64][64];
    __shared__ float Vl[64][65];
    const ushort* Kg = kh + (size_t)(b * 1024 + c * 64) * 64;
    for (int i = tid; i < 1024; i += 256) {
        ushort4 k4 = ((const ushort4*)Kg)[i];
        ((float4*)Kl)[i] = make_float4(b2f(k4.x), b2f(k4.y), b2f(k4.z), b2f(k4.w));
        int e = i >> 4, s4 = (i & 15) << 2;
        ushort4 v4 = *(const ushort4*)&vt[(size_t)(b * 64 + e) * 1024 + c * 64 + s4];
        Vl[e][s4 + 0] = b2f(v4.x); Vl[e][s4 + 1] = b2f(v4.y);
        Vl[e][s4 + 2] = b2f(v4.z); Vl[e][s4 + 3] = b2f(v4.w);
    }
    __syncthreads();
    int e = tid & 63, d0 = (tid >> 6) * 16;
    float s[16] = {};
    for (int ss = 0; ss < 64; ss++) {
        float ve = Vl[e][ss];
        #pragma unroll
        for (int i = 0; i < 16; i++) s[i] += Kl[ss][d0 + i] * ve;
    }
    float* So = St + (size_t)(b * 16 + c) * 4096 + e * 64 + d0;
    #pragma unroll
    for (int k = 0; k < 4; k++)
        *(float4*)&So[k * 4] = make_float4(s[4*k], s[4*k+1], s[4*k+2], s[4*k+3]);
    if (tid < 64) {
        float z = 0.f;
        for (int ss = 0; ss < 64; ss++) z += Kl[ss][tid];
        zc[(size_t)(b * 16 + c) * 64 + tid] = z;
    }
}

// exclusive prefix over chunks: St (f32) -> Spt (bf16), zc in-place
__global__ __launch_bounds__(256) void prefix_chunks(const float* __restrict__ St,
                                                     ushort* __restrict__ Spt,
                                                     float* __restrict__ zc) {
    int b = blockIdx.x, tid = threadIdx.x;
    size_t base = (size_t)b * 16 * 4096 + (size_t)tid * 16;
    float run[16] = {};
    for (int c = 0; c < 16; c++) {
        const float4* p4 = (const float4*)(St + base + (size_t)c * 4096);
        ushort* q = Spt + base + (size_t)c * 4096;
        #pragma unroll
        for (int k = 0; k < 4; k++) {
            float4 v = p4[k];
            ushort4 o;
            o.x = f2b(run[4*k+0]); o.y = f2b(run[4*k+1]);
            o.z = f2b(run[4*k+2]); o.w = f2b(run[4*k+3]);
            ((ushort4*)q)[k] = o;
            run[4*k+0] += v.x; run[4*k+1] += v.y; run[4*k+2] += v.z; run[4*k+3] += v.w;
        }
    }
    if (tid < 64) {
        float rz = 0.f;
        for (int c = 0; c < 16; c++) {
            size_t idx = ((size_t)b * 16 + c) * 64 + tid;
            float t = zc[idx];
            zc[idx] = rz;
            rz += t;
        }
    }
}

// ---------------------------------------------------------------------------
// MFMA attention per (b, c): P = phiQ phiK^T (masked), num = phiQ S_prev + P V,
// den = phiQ z_prev + rowsum(P); attn = num/den (bf16)
// All LDS tiles 64x64 bf16, XOR-swizzled (key = row&7 on 16B slots).
// 4 waves; wave w owns t-strip [w*16, w*16+16).
// ---------------------------------------------------------------------------
__global__ __launch_bounds__(256) void attn_chunk(const ushort* __restrict__ qh,
                                                  const ushort* __restrict__ kh,
                                                  const ushort* __restrict__ vt,
                                                  const ushort* __restrict__ Spt,
                                                  const float* __restrict__ zc,
                                                  ushort* __restrict__ attn) {
    int c = blockIdx.x, b = blockIdx.y, tid = threadIdx.x;
    int w = tid >> 6, lane = tid & 63;
    int fr = lane & 15, hi = lane >> 4;
    __shared__ ushort Q[4096], Kt[4096], VT[4096], SP[4096], P[4096];
    __shared__ float den[64];

    // stage 4 tiles (8KB each) via gload16, pre-swizzled source
    {
        const ushort* bases[4];
        bases[0] = qh + (size_t)(b * 1024 + c * 64) * 64;
        bases[1] = kh + (size_t)(b * 1024 + c * 64) * 64;
        bases[2] = vt;   // row-stride 1024, offset below
        bases[3] = Spt + (size_t)(b * 16 + c) * 4096;
        ushort* dsts[4] = {Q, Kt, VT, SP};
        #pragma unroll
        for (int tl = 0; tl < 4; tl++) {
            #pragma unroll
            for (int j = 0; j < 2; j++) {
                int i = w * 64 + lane + 256 * j;
                int row = i >> 3, sl = i & 7;
                int col = (sl ^ (row & 7)) * 8;
                const ushort* src;
                if (tl == 2) src = vt + (size_t)(b * 64 + row) * 1024 + c * 64 + col;
                else         src = bases[tl] + (size_t)row * 64 + col;
                gload16(src, dsts[tl] + w * 512 + 2048 * j);
            }
        }
    }
    __syncthreads();

    // phase A: P = QK^T   (A = Q rows t=w*16+fr ; B = K rows s=n*16+fr; key=fr&7)
    int frow = w * 16 + fr;
    int fkey = fr & 7;
    bf16x8 aq[2];
    #pragma unroll
    for (int kk = 0; kk < 2; kk++)
        aq[kk] = *(const bf16x8*)&Q[frow * 64 + ((kk * 4 + hi) ^ fkey) * 8];
    f32x4 pc[4];
    #pragma unroll
    for (int n = 0; n < 4; n++) {
        pc[n] = (f32x4){0.f, 0.f, 0.f, 0.f};
        #pragma unroll
        for (int kk = 0; kk < 2; kk++) {
            bf16x8 bk_ = *(const bf16x8*)&Kt[(n * 16 + fr) * 64 + ((kk * 4 + hi) ^ fkey) * 8];
            pc[n] = __builtin_amdgcn_mfma_f32_16x16x32_bf16(aq[kk], bk_, pc[n], 0, 0, 0);
        }
    }
    // mask (s<=t), den partials, write P (bf16, swizzled rows t)
    float denp[4] = {0.f, 0.f, 0.f, 0.f};
    #pragma unroll
    for (int n = 0; n < 4; n++)
        #pragma unroll
        for (int r = 0; r < 4; r++) {
            int t = w * 16 + hi * 4 + r;
            int s = n * 16 + fr;
            float v = (s <= t) ? pc[n][r] : 0.f;
            denp[r] += v;
            P[t * 64 + (((s >> 3) ^ (t & 7)) * 8) + (s & 7)] = f2b(v);
        }
    #pragma unroll
    for (int r = 0; r < 4; r++) {
        denp[r] += __shfl_xor(denp[r], 1);
        denp[r] += __shfl_xor(denp[r], 2);
        denp[r] += __shfl_xor(denp[r], 4);
        denp[r] += __shfl_xor(denp[r], 8);
    }
    if (fr == 0) {
        #pragma unroll
        for (int r = 0; r < 4; r++) den[w * 16 + hi * 4 + r] = denp[r];
    }
    __syncthreads();

    // qz: den[t] += phiQ[t] . z_prev  (wave 0 only, scalar)
    if (tid < 64) {
        int t = tid;
        const float* zg = zc + (size_t)(b * 16 + c) * 64;
        float a = 0.f;
        for (int d = 0; d < 64; d++)
            a += b2f(Q[t * 64 + (((d >> 3) ^ (t & 7)) * 8) + (d & 7)]) * zg[d];
        den[t] += a;
    }

    // phase B: num = Q @ SP^T-rows  +  P @ VT-rows   (C[t][e])
    bf16x8 ap[2];
    #pragma unroll
    for (int kk = 0; kk < 2; kk++)
        ap[kk] = *(const bf16x8*)&P[frow * 64 + ((kk * 4 + hi) ^ fkey) * 8];
    f32x4 nacc[4];
    #pragma unroll
    for (int n = 0; n < 4; n++) {
        nacc[n] = (f32x4){0.f, 0.f, 0.f, 0.f};
        #pragma unroll
        for (int kk = 0; kk < 2; kk++) {
            bf16x8 bs = *(const bf16x8*)&SP[(n * 16 + fr) * 64 + ((kk * 4 + hi) ^ fkey) * 8];
            nacc[n] = __builtin_amdgcn_mfma_f32_16x16x32_bf16(aq[kk], bs, nacc[n], 0, 0, 0);
        }
        #pragma unroll
        for (int kk = 0; kk < 2; kk++) {
            bf16x8 bv = *(const bf16x8*)&VT[(n * 16 + fr) * 64 + ((kk * 4 + hi) ^ fkey) * 8];
            nacc[n] = __builtin_amdgcn_mfma_f32_16x16x32_bf16(ap[kk], bv, nacc[n], 0, 0, 0);
        }
    }
    __syncthreads();   // den complete

    int nb = b >> 4, h = b & 15;
    #pragma unroll
    for (int n = 0; n < 4; n++)
        #pragma unroll
        for (int r = 0; r < 4; r++) {
            int t = w * 16 + hi * 4 + r;
            int e = n * 16 + fr;
            int l = c * 64 + t;
            float val = nacc[n][r] / (den[t] + EPS);
            attn[(size_t)(l * 2 + nb) * 1024 + h * 64 + e] = f2b(val);
        }
}

// ---------------------------------------------------------------------------
extern "C" void kernel_launch(void* const* d_in, const int* in_sizes, int n_in,
                              void* d_out, int out_size, void* d_ws, size_t ws_size,
                              hipStream_t stream) {
    const float* query = (const float*)d_in[0];
    const float* key_  = (const float*)d_in[1];
    const float* value = (const float*)d_in[2];
    const float* Wq = (const float*)d_in[3];
    const float* bq = (const float*)d_in[4];
    const float* Wk = (const float*)d_in[5];
    const float* bk = (const float*)d_in[6];
    const float* Wv = (const float*)d_in[7];
    const float* bv = (const float*)d_in[8];
    const float* Wo = (const float*)d_in[9];
    const float* bo = (const float*)d_in[10];

    // workspace layout
    ushort* qbuf = (ushort*)d_ws;          // 2M u16
    ushort* kbuf = qbuf + 2097152;
    ushort* vbuf = kbuf + 2097152;
    ushort* wqb  = vbuf + 2097152;         // 1M u16 x4
    ushort* wkb  = wqb + 1048576;
    ushort* wvb  = wkb + 1048576;
    ushort* wob  = wvb + 1048576;
    ushort* qh   = wob + 1048576;          // 2M u16
    ushort* kh   = qh + 2097152;
    ushort* vt   = kh + 2097152;
    float*  St   = (float*)(vt + 2097152); // 2M f32
    ushort* Spt  = (ushort*)(St + 2097152);// 2M u16
    float*  zc   = (float*)(Spt + 2097152);// 32K f32
    float*  pbuf = zc + 32768;             // 4 x 2M f32 (split-K partials)
    ushort* attn = qbuf;                   // qbuf dead after proj

    cast_all<<<dim3(2048, 1, 7), 256, 0, stream>>>(query, key_, value, Wq, Wk, Wv, Wo,
                                                   qbuf, kbuf, vbuf, wqb, wkb, wvb, wob);

    gemm_proj<<<dim3(8, 32, 3), 128, 0, stream>>>(qbuf, kbuf, vbuf, wqb, wkb, wvb,
                                                  bq, bk, bv, qh, kh, vt);

    chunk_sums<<<dim3(16, 32), 256, 0, stream>>>(kh, vt, St, zc);
    prefix_chunks<<<32, 256, 0, stream>>>(St, Spt, zc);
    attn_chunk<<<dim3(16, 32), 256, 0, stream>>>(qh, kh, vt, Spt, zc, attn);

    gemm_outk<<<dim3(8, 32, 4), 128, 0, stream>>>(attn, wob, pbuf);
    reduce_out<<<2048, 256, 0, stream>>>(pbuf, bo, (float*)d_out);
}

// Round 5
// 92.215 us; speedup vs baseline: 3.8010x; 1.0516x over previous
//
#include <hip/hip_runtime.h>
#include <cmath>

// L=1024, N=2, E=1024, H=16, d=64, B*H=32 heads, chunk C=64, NC=16 chunks
// qh/kh: [b=32][l=1024][d=64] bf16 ; vt: [b=32][e=64][l=1024] bf16
// St/Spt: [b][c][e=64][d=64] (S^T, exclusive prefix in Spt) ; zc: [b][c][64] f32
// attn rows m = l*2 + nb, cols h*64+e

#define EPS 1e-6f

typedef short bf16x8 __attribute__((ext_vector_type(8)));
typedef float f32x4 __attribute__((ext_vector_type(4)));

__device__ __forceinline__ float b2f(ushort u) {
    union { unsigned u32; float f; } x; x.u32 = ((unsigned)u) << 16; return x.f;
}
__device__ __forceinline__ ushort f2b(float f) {
    union { float f; unsigned u; } x; x.f = f;
    unsigned r = (x.u + 0x7fffu + ((x.u >> 16) & 1u)) >> 16;
    return (ushort)r;
}
__device__ __forceinline__ void gload16(const void* g, void* l) {
    __builtin_amdgcn_global_load_lds(
        (__attribute__((address_space(1))) void*)(uintptr_t)g,
        (__attribute__((address_space(3))) void*)l,
        16, 0, 0);
}

// ---------------------------------------------------------------------------
// bf16 MFMA GEMM mainloop: C[m][n] = sum_k A[m][k]*B[n][k] (row-major, K=1024)
// Tile 64(M) x 128(N), BK=32, 128 threads = 2 waves, each wave 64x64.
// Counted-vmcnt pipeline (T3+T4): depth-2 prefetch, 4 LDS buffers (48KB).
// Per iter t: stage(t+2) -> s_waitcnt vmcnt(12) -> s_barrier -> read buf[t%4].
//   - vmcnt(12): 6 loads/step/wave in flight for steps t+1,t+2 => step t done.
//   - barrier: every wave waited its own vmcnt first => ALL staging of step t
//     visible to all waves. NB=4 >= D+2 so a fast wave's stage(t+1+D) never
//     touches the buffer a slow wave still reads (one barrier per step).
// Swizzle key (row>>1)&3 on 16B slots, both sides (pre-swizzled global source).
// ---------------------------------------------------------------------------
template<int NSTEPS>
__device__ __forceinline__ void gemm_mainloop2(const ushort* __restrict__ A,
                                               const ushort* __restrict__ B,
                                               int brow, int bcol, int kbeg,
                                               ushort* Sh, f32x4 acc[4][4]) {
    const int K = 1024;
    const int BUF = 6144;   // elems per buffer: A 64x32 + B 128x32
    int tid = threadIdx.x;
    int w = tid >> 6, lane = tid & 63;
    int fr = lane & 15, hi = lane >> 4;

    // staging: per thread 2 A-gloads + 4 B-gloads, 16B each
    int srow = lane >> 2;                     // 0..15 within 16-row group
    int ssl  = lane & 3;                      // dest slot
    int arowA = (w * 2) * 16 + srow;          // A inst j rows (w*2+j)*16+srow
    int arowB = (w * 4) * 16 + srow;          // B inst j rows (w*4+j)*16+srow
    const ushort* Ag = A + (size_t)(brow + arowA) * K + kbeg + ((ssl ^ ((arowA >> 1) & 3)) * 8);
    const ushort* Bg = B + (size_t)(bcol + arowB) * K + kbeg + ((ssl ^ ((arowB >> 1) & 3)) * 8);
    int adst = w * 1024;                      // wave-uniform LDS elem offsets
    int bdst = 2048 + w * 2048;

    // fragment offsets: key = (fr>>1)&3 uniform per lane
    int fkey = (fr >> 1) & 3;
    int ea[4], eb[4];
    #pragma unroll
    for (int m = 0; m < 4; m++) ea[m] = (m * 16 + fr) * 32 + ((hi ^ fkey) * 8);
    #pragma unroll
    for (int n = 0; n < 4; n++) eb[n] = 2048 + (w * 64 + n * 16 + fr) * 32 + ((hi ^ fkey) * 8);

    #pragma unroll
    for (int m = 0; m < 4; m++)
        #pragma unroll
        for (int n = 0; n < 4; n++)
            acc[m][n] = (f32x4){0.f, 0.f, 0.f, 0.f};

    // prologue: stage steps 0,1 into buffers 0,1 (no barrier needed yet)
    #pragma unroll
    for (int p = 0; p < 2; p++) {
        ushort* Sn = Sh + p * BUF;
        int k0 = p * 32;
        #pragma unroll
        for (int j = 0; j < 2; j++) gload16(Ag + k0 + (size_t)j * 16 * K, Sn + adst + j * 512);
        #pragma unroll
        for (int j = 0; j < 4; j++) gload16(Bg + k0 + (size_t)j * 16 * K, Sn + bdst + j * 512);
    }

    for (int t = 0; t < NSTEPS; ++t) {
        if (t + 2 < NSTEPS) {
            int k0 = (t + 2) * 32;
            ushort* Sn = Sh + ((t + 2) & 3) * BUF;
            #pragma unroll
            for (int j = 0; j < 2; j++) gload16(Ag + k0 + (size_t)j * 16 * K, Sn + adst + j * 512);
            #pragma unroll
            for (int j = 0; j < 4; j++) gload16(Bg + k0 + (size_t)j * 16 * K, Sn + bdst + j * 512);
        }
        // own loads for step t complete (6/step in flight for t+1,t+2)
        if (t + 2 < NSTEPS)      asm volatile("s_waitcnt vmcnt(12)" ::: "memory");
        else if (t + 1 < NSTEPS) asm volatile("s_waitcnt vmcnt(6)" ::: "memory");
        else                     asm volatile("s_waitcnt vmcnt(0)" ::: "memory");
        __builtin_amdgcn_s_barrier();          // all waves' stage(t) now visible
        __builtin_amdgcn_sched_barrier(0);     // pin: no ds_read hoisted above
        const ushort* Sc_ = Sh + (t & 3) * BUF;
        bf16x8 af[4], bf[4];
        #pragma unroll
        for (int m = 0; m < 4; m++) af[m] = *(const bf16x8*)&Sc_[ea[m]];
        #pragma unroll
        for (int n = 0; n < 4; n++) bf[n] = *(const bf16x8*)&Sc_[eb[n]];
        #pragma unroll
        for (int m = 0; m < 4; m++)
            #pragma unroll
            for (int n = 0; n < 4; n++)
                acc[m][n] = __builtin_amdgcn_mfma_f32_16x16x32_bf16(af[m], bf[n], acc[m][n], 0, 0, 0);
    }
}

// proj GEMMs: z=0 q(phi)->qh, z=1 k(phi)->kh, z=2 v->vt (transposed head layout)
__global__ __launch_bounds__(128) void gemm_proj(
    const ushort* __restrict__ Aq, const ushort* __restrict__ Ak, const ushort* __restrict__ Av,
    const ushort* __restrict__ Bq, const ushort* __restrict__ Bk, const ushort* __restrict__ Bv,
    const float* __restrict__ bq, const float* __restrict__ bk, const float* __restrict__ bv,
    ushort* __restrict__ oq, ushort* __restrict__ ok, ushort* __restrict__ ov) {
    __shared__ ushort Sh[4 * 6144];
    int z = blockIdx.z;
    const ushort* A = (z == 0) ? Aq : (z == 1) ? Ak : Av;
    const ushort* B = (z == 0) ? Bq : (z == 1) ? Bk : Bv;
    const float* bias = (z == 0) ? bq : (z == 1) ? bk : bv;
    int brow = blockIdx.y * 64, bcol = blockIdx.x * 128;
    f32x4 acc[4][4];
    gemm_mainloop2<32>(A, B, brow, bcol, 0, Sh, acc);
    int tid = threadIdx.x, w = tid >> 6, lane = tid & 63;
    int fr = lane & 15, hi = lane >> 4;
    #pragma unroll
    for (int m = 0; m < 4; m++)
        #pragma unroll
        for (int n = 0; n < 4; n++)
            #pragma unroll
            for (int r = 0; r < 4; r++) {
                int grow = brow + m * 16 + hi * 4 + r;
                int gcol = bcol + w * 64 + n * 16 + fr;
                float v = acc[m][n][r] + bias[gcol];
                int l = grow >> 1, nb2 = grow & 1, h = gcol >> 6, dd = gcol & 63;
                if (z == 2) {
                    ov[(size_t)((nb2 * 16 + h) * 64 + dd) * 1024 + l] = f2b(v);
                } else {
                    v = (v > 0.f) ? v + 1.f : __expf(v);
                    ushort* out = (z == 0) ? oq : ok;
                    out[(size_t)((nb2 * 16 + h) * 1024 + l) * 64 + dd] = f2b(v);
                }
            }
}

// out GEMM, split-K=4: partial[z][m][n] = sum_{k in z-slice} attn[m][k]*Wo[n][k]
__global__ __launch_bounds__(128) void gemm_outk(const ushort* __restrict__ A,
                                                 const ushort* __restrict__ B,
                                                 float* __restrict__ pbuf) {
    __shared__ ushort Sh[4 * 6144];
    int brow = blockIdx.y * 64, bcol = blockIdx.x * 128, z = blockIdx.z;
    f32x4 acc[4][4];
    gemm_mainloop2<8>(A, B, brow, bcol, z * 256, Sh, acc);
    int tid = threadIdx.x, w = tid >> 6, lane = tid & 63;
    int fr = lane & 15, hi = lane >> 4;
    float* out = pbuf + (size_t)z * 2097152;
    #pragma unroll
    for (int m = 0; m < 4; m++)
        #pragma unroll
        for (int n = 0; n < 4; n++)
            #pragma unroll
            for (int r = 0; r < 4; r++) {
                int grow = brow + m * 16 + hi * 4 + r;
                int gcol = bcol + w * 64 + n * 16 + fr;
                out[(size_t)grow * 1024 + gcol] = acc[m][n][r];
            }
}

__global__ __launch_bounds__(256) void reduce_out(const float* __restrict__ p,
                                                  const float* __restrict__ bias,
                                                  float* __restrict__ out) {
    int i = blockIdx.x * 256 + threadIdx.x;      // over 524288 float4s
    float4 a = ((const float4*)p)[i];
    float4 b = ((const float4*)(p + 2097152))[i];
    float4 c = ((const float4*)(p + 4194304))[i];
    float4 d = ((const float4*)(p + 6291456))[i];
    float4 bb = ((const float4*)bias)[i & 255];
    float4 o;
    o.x = a.x + b.x + c.x + d.x + bb.x;
    o.y = a.y + b.y + c.y + d.y + bb.y;
    o.z = a.z + b.z + c.z + d.z + bb.z;
    o.w = a.w + b.w + c.w + d.w + bb.w;
    ((float4*)out)[i] = o;
}

// ---------------------------------------------------------------------------
// merged f32 -> bf16 cast: z 0..2 -> q,k,v (2M elems); z 3..6 -> Wq,Wk,Wv,Wo (1M)
// ---------------------------------------------------------------------------
__global__ __launch_bounds__(256) void cast_all(
    const float* __restrict__ i0, const float* __restrict__ i1, const float* __restrict__ i2,
    const float* __restrict__ i3, const float* __restrict__ i4, const float* __restrict__ i5,
    const float* __restrict__ i6,
    ushort* __restrict__ o0, ushort* __restrict__ o1, ushort* __restrict__ o2,
    ushort* __restrict__ o3, ushort* __restrict__ o4, ushort* __restrict__ o5,
    ushort* __restrict__ o6) {
    int z = blockIdx.z;
    const float* in = (z == 0) ? i0 : (z == 1) ? i1 : (z == 2) ? i2 :
                      (z == 3) ? i3 : (z == 4) ? i4 : (z == 5) ? i5 : i6;
    ushort* out = (z == 0) ? o0 : (z == 1) ? o1 : (z == 2) ? o2 :
                  (z == 3) ? o3 : (z == 4) ? o4 : (z == 5) ? o5 : o6;
    int n4 = (z < 3) ? 524288 : 262144;
    int i = blockIdx.x * 256 + threadIdx.x;
    if (i < n4) {
        float4 f = ((const float4*)in)[i];
        ushort4 o; o.x = f2b(f.x); o.y = f2b(f.y); o.z = f2b(f.z); o.w = f2b(f.w);
        ((ushort4*)out)[i] = o;
    }
}

// ---------------------------------------------------------------------------
// Per-(head, chunk) KV sums, transposed out: St[b][c][e][d] = sum_s v[s][e]*k[s][d]
// zc[b][c][d] = sum_s k[s][d]
// ---------------------------------------------------------------------------
__global__ __launch_bounds__(256) void chunk_sums(const ushort* __restrict__ kh,
                                                  const ushort* __restrict__ vt,
                                                  float* __restrict__ St,
                                                  float* __restrict__ zc) {
    int c = blockIdx.x, b = blockIdx.y, tid = threadIdx.x;
    __shared__ float Kl[64][64];
    __shared__ float Vl[64][65];
    const ushort* Kg = kh + (size_t)(b * 1024 + c * 64) * 64;
    for (int i = tid; i < 1024; i += 256) {
        ushort4 k4 = ((const ushort4*)Kg)[i];
        ((float4*)Kl)[i] = make_float4(b2f(k4.x), b2f(k4.y), b2f(k4.z), b2f(k4.w));
        int e = i >> 4, s4 = (i & 15) << 2;
        ushort4 v4 = *(const ushort4*)&vt[(size_t)(b * 64 + e) * 1024 + c * 64 + s4];
        Vl[e][s4 + 0] = b2f(v4.x); Vl[e][s4 + 1] = b2f(v4.y);
        Vl[e][s4 + 2] = b2f(v4.z); Vl[e][s4 + 3] = b2f(v4.w);
    }
    __syncthreads();
    int e = tid & 63, d0 = (tid >> 6) * 16;
    float s[16] = {};
    for (int ss = 0; ss < 64; ss++) {
        float ve = Vl[e][ss];
        #pragma unroll
        for (int i = 0; i < 16; i++) s[i] += Kl[ss][d0 + i] * ve;
    }
    float* So = St + (size_t)(b * 16 + c) * 4096 + e * 64 + d0;
    #pragma unroll
    for (int k = 0; k < 4; k++)
        *(float4*)&So[k * 4] = make_float4(s[4*k], s[4*k+1], s[4*k+2], s[4*k+3]);
    if (tid < 64) {
        float z = 0.f;
        for (int ss = 0; ss < 64; ss++) z += Kl[ss][tid];
        zc[(size_t)(b * 16 + c) * 64 + tid] = z;
    }
}

// exclusive prefix over chunks: St (f32) -> Spt (bf16), zc in-place
__global__ __launch_bounds__(256) void prefix_chunks(const float* __restrict__ St,
                                                     ushort* __restrict__ Spt,
                                                     float* __restrict__ zc) {
    int b = blockIdx.x, tid = threadIdx.x;
    size_t base = (size_t)b * 16 * 4096 + (size_t)tid * 16;
    float run[16] = {};
    for (int c = 0; c < 16; c++) {
        const float4* p4 = (const float4*)(St + base + (size_t)c * 4096);
        ushort* q = Spt + base + (size_t)c * 4096;
        #pragma unroll
        for (int k = 0; k < 4; k++) {
            float4 v = p4[k];
            ushort4 o;
            o.x = f2b(run[4*k+0]); o.y = f2b(run[4*k+1]);
            o.z = f2b(run[4*k+2]); o.w = f2b(run[4*k+3]);
            ((ushort4*)q)[k] = o;
            run[4*k+0] += v.x; run[4*k+1] += v.y; run[4*k+2] += v.z; run[4*k+3] += v.w;
        }
    }
    if (tid < 64) {
        float rz = 0.f;
        for (int c = 0; c < 16; c++) {
            size_t idx = ((size_t)b * 16 + c) * 64 + tid;
            float t = zc[idx];
            zc[idx] = rz;
            rz += t;
        }
    }
}

// ---------------------------------------------------------------------------
// MFMA attention per (b, c): P = phiQ phiK^T (masked), num = phiQ S_prev + P V,
// den = phiQ z_prev + rowsum(P); attn = num/den (bf16)
// All LDS tiles 64x64 bf16, XOR-swizzled (key = row&7 on 16B slots).
// ---------------------------------------------------------------------------
__global__ __launch_bounds__(256) void attn_chunk(const ushort* __restrict__ qh,
                                                  const ushort* __restrict__ kh,
                                                  const ushort* __restrict__ vt,
                                                  const ushort* __restrict__ Spt,
                                                  const float* __restrict__ zc,
                                                  ushort* __restrict__ attn) {
    int c = blockIdx.x, b = blockIdx.y, tid = threadIdx.x;
    int w = tid >> 6, lane = tid & 63;
    int fr = lane & 15, hi = lane >> 4;
    __shared__ ushort Q[4096], Kt[4096], VT[4096], SP[4096], P[4096];
    __shared__ float den[64];

    // stage 4 tiles (8KB each) via gload16, pre-swizzled source
    {
        const ushort* bases[4];
        bases[0] = qh + (size_t)(b * 1024 + c * 64) * 64;
        bases[1] = kh + (size_t)(b * 1024 + c * 64) * 64;
        bases[2] = vt;   // row-stride 1024, offset below
        bases[3] = Spt + (size_t)(b * 16 + c) * 4096;
        ushort* dsts[4] = {Q, Kt, VT, SP};
        #pragma unroll
        for (int tl = 0; tl < 4; tl++) {
            #pragma unroll
            for (int j = 0; j < 2; j++) {
                int i = w * 64 + lane + 256 * j;
                int row = i >> 3, sl = i & 7;
                int col = (sl ^ (row & 7)) * 8;
                const ushort* src;
                if (tl == 2) src = vt + (size_t)(b * 64 + row) * 1024 + c * 64 + col;
                else         src = bases[tl] + (size_t)row * 64 + col;
                gload16(src, dsts[tl] + w * 512 + 2048 * j);
            }
        }
    }
    __syncthreads();

    // phase A: P = QK^T
    int frow = w * 16 + fr;
    int fkey = fr & 7;
    bf16x8 aq[2];
    #pragma unroll
    for (int kk = 0; kk < 2; kk++)
        aq[kk] = *(const bf16x8*)&Q[frow * 64 + ((kk * 4 + hi) ^ fkey) * 8];
    f32x4 pc[4];
    #pragma unroll
    for (int n = 0; n < 4; n++) {
        pc[n] = (f32x4){0.f, 0.f, 0.f, 0.f};
        #pragma unroll
        for (int kk = 0; kk < 2; kk++) {
            bf16x8 bk_ = *(const bf16x8*)&Kt[(n * 16 + fr) * 64 + ((kk * 4 + hi) ^ fkey) * 8];
            pc[n] = __builtin_amdgcn_mfma_f32_16x16x32_bf16(aq[kk], bk_, pc[n], 0, 0, 0);
        }
    }
    // mask (s<=t), den partials, write P (bf16, swizzled rows t)
    float denp[4] = {0.f, 0.f, 0.f, 0.f};
    #pragma unroll
    for (int n = 0; n < 4; n++)
        #pragma unroll
        for (int r = 0; r < 4; r++) {
            int t = w * 16 + hi * 4 + r;
            int s = n * 16 + fr;
            float v = (s <= t) ? pc[n][r] : 0.f;
            denp[r] += v;
            P[t * 64 + (((s >> 3) ^ (t & 7)) * 8) + (s & 7)] = f2b(v);
        }
    #pragma unroll
    for (int r = 0; r < 4; r++) {
        denp[r] += __shfl_xor(denp[r], 1);
        denp[r] += __shfl_xor(denp[r], 2);
        denp[r] += __shfl_xor(denp[r], 4);
        denp[r] += __shfl_xor(denp[r], 8);
    }
    if (fr == 0) {
        #pragma unroll
        for (int r = 0; r < 4; r++) den[w * 16 + hi * 4 + r] = denp[r];
    }
    __syncthreads();

    // qz: den[t] += phiQ[t] . z_prev  (wave 0 only, scalar)
    if (tid < 64) {
        int t = tid;
        const float* zg = zc + (size_t)(b * 16 + c) * 64;
        float a = 0.f;
        for (int d = 0; d < 64; d++)
            a += b2f(Q[t * 64 + (((d >> 3) ^ (t & 7)) * 8) + (d & 7)]) * zg[d];
        den[t] += a;
    }

    // phase B: num = Q @ SP-rows + P @ VT-rows   (C[t][e])
    bf16x8 ap[2];
    #pragma unroll
    for (int kk = 0; kk < 2; kk++)
        ap[kk] = *(const bf16x8*)&P[frow * 64 + ((kk * 4 + hi) ^ fkey) * 8];
    f32x4 nacc[4];
    #pragma unroll
    for (int n = 0; n < 4; n++) {
        nacc[n] = (f32x4){0.f, 0.f, 0.f, 0.f};
        #pragma unroll
        for (int kk = 0; kk < 2; kk++) {
            bf16x8 bs = *(const bf16x8*)&SP[(n * 16 + fr) * 64 + ((kk * 4 + hi) ^ fkey) * 8];
            nacc[n] = __builtin_amdgcn_mfma_f32_16x16x32_bf16(aq[kk], bs, nacc[n], 0, 0, 0);
        }
        #pragma unroll
        for (int kk = 0; kk < 2; kk++) {
            bf16x8 bv = *(const bf16x8*)&VT[(n * 16 + fr) * 64 + ((kk * 4 + hi) ^ fkey) * 8];
            nacc[n] = __builtin_amdgcn_mfma_f32_16x16x32_bf16(ap[kk], bv, nacc[n], 0, 0, 0);
        }
    }
    __syncthreads();   // den complete

    int nb = b >> 4, h = b & 15;
    #pragma unroll
    for (int n = 0; n < 4; n++)
        #pragma unroll
        for (int r = 0; r < 4; r++) {
            int t = w * 16 + hi * 4 + r;
            int e = n * 16 + fr;
            int l = c * 64 + t;
            float val = nacc[n][r] / (den[t] + EPS);
            attn[(size_t)(l * 2 + nb) * 1024 + h * 64 + e] = f2b(val);
        }
}

// ---------------------------------------------------------------------------
extern "C" void kernel_launch(void* const* d_in, const int* in_sizes, int n_in,
                              void* d_out, int out_size, void* d_ws, size_t ws_size,
                              hipStream_t stream) {
    const float* query = (const float*)d_in[0];
    const float* key_  = (const float*)d_in[1];
    const float* value = (const float*)d_in[2];
    const float* Wq = (const float*)d_in[3];
    const float* bq = (const float*)d_in[4];
    const float* Wk = (const float*)d_in[5];
    const float* bk = (const float*)d_in[6];
    const float* Wv = (const float*)d_in[7];
    const float* bv = (const float*)d_in[8];
    const float* Wo = (const float*)d_in[9];
    const float* bo = (const float*)d_in[10];

    // workspace layout
    ushort* qbuf = (ushort*)d_ws;          // 2M u16
    ushort* kbuf = qbuf + 2097152;
    ushort* vbuf = kbuf + 2097152;
    ushort* wqb  = vbuf + 2097152;         // 1M u16 x4
    ushort* wkb  = wqb + 1048576;
    ushort* wvb  = wkb + 1048576;
    ushort* wob  = wvb + 1048576;
    ushort* qh   = wob + 1048576;          // 2M u16
    ushort* kh   = qh + 2097152;
    ushort* vt   = kh + 2097152;
    float*  St   = (float*)(vt + 2097152); // 2M f32
    ushort* Spt  = (ushort*)(St + 2097152);// 2M u16
    float*  zc   = (float*)(Spt + 2097152);// 32K f32
    float*  pbuf = zc + 32768;             // 4 x 2M f32 (split-K partials)
    ushort* attn = qbuf;                   // qbuf dead after proj

    cast_all<<<dim3(2048, 1, 7), 256, 0, stream>>>(query, key_, value, Wq, Wk, Wv, Wo,
                                                   qbuf, kbuf, vbuf, wqb, wkb, wvb, wob);

    gemm_proj<<<dim3(8, 32, 3), 128, 0, stream>>>(qbuf, kbuf, vbuf, wqb, wkb, wvb,
                                                  bq, bk, bv, qh, kh, vt);

    chunk_sums<<<dim3(16, 32), 256, 0, stream>>>(kh, vt, St, zc);
    prefix_chunks<<<32, 256, 0, stream>>>(St, Spt, zc);
    attn_chunk<<<dim3(16, 32), 256, 0, stream>>>(qh, kh, vt, Spt, zc, attn);

    gemm_outk<<<dim3(8, 32, 4), 128, 0, stream>>>(attn, wob, pbuf);
    reduce_out<<<2048, 256, 0, stream>>>(pbuf, bo, (float*)d_out);
}